// Round 19
// baseline (269.416 us; speedup 1.0000x reference)
//
#include <hip/hip_runtime.h>

// ---------------------------------------------------------------------------
// Fused full attention (V, A). B=4 L=S=2048 H=8 E=64, fp32 in/out.
// r14 base (verified 190.9us twice; setprio removed — r17 showed -7us) with
// ONE change: A-flush uses PLAIN cached stores instead of nontemporal.
// Rationale: fill kernel sustains 6.75 TB/s via the L2 write-back path;
// nt-stores bypass L2 write-combining and our A stream sits at ~4.3 TB/s.
// A is write-once (caching useless) but the cached WRITE PATH may be faster.
// Structure: 1 q-tile (64 rows) per 256-thr WG, grid 1024; two K-sweeps:
//   sweep1: l = sum exp2(s*SC2+MB2)           [K staged, dbuf, vmcnt(1)]
//   sweep2: A = p*rinv via a_lds full-line flush; PV from vt_lds [vmcnt(5)]
// Stage->sched_barrier->body->counted-vmcnt->s_barrier per chunk.
// ---------------------------------------------------------------------------

typedef __attribute__((ext_vector_type(8))) short bf16x8;
typedef __attribute__((ext_vector_type(4))) short bf16x4;
typedef __attribute__((ext_vector_type(4))) float f32x4;

#define NB 4
#define NL 2048
#define NS 2048
#define NH 8
#define NE 64
#define SKC 64
#define NT (NS / SKC)
#define AW 68   // padded a_lds row stride (floats)
// exp(s*0.125 - 4) == exp2(s*SC2 + MB2)
#define SC2 0.18033688011112042f
#define MB2 -5.770780163555854f
#define EXP2(x) __builtin_amdgcn_exp2f(x)

static __device__ __forceinline__ short f2bf(float x) {
  unsigned u = __builtin_bit_cast(unsigned, x);
  u += 0x7fffu + ((u >> 16) & 1u);   // round-to-nearest-even
  return (short)(u >> 16);
}

static __device__ __forceinline__ bf16x8 pack8(f32x4 a, f32x4 b) {
  bf16x8 t;
  t[0] = f2bf(a[0]); t[1] = f2bf(a[1]); t[2] = f2bf(a[2]); t[3] = f2bf(a[3]);
  t[4] = f2bf(b[0]); t[5] = f2bf(b[1]); t[6] = f2bf(b[2]); t[7] = f2bf(b[3]);
  return t;
}

// ---------------- merged prep kernel ----------------
__global__ __launch_bounds__(256)
void prep_all(const float* __restrict__ K, const float* __restrict__ V,
              const int* __restrict__ M, short* __restrict__ Kb,
              short* __restrict__ Vt, unsigned long long* __restrict__ Mb) {
  __shared__ short t_lds[64 * 65];
  const int bid = blockIdx.x, tid = threadIdx.x;
  if (bid < 4096) {
    long i4 = ((long)bid * 256 + tid) * 4;
    f32x4 v = *(const f32x4*)(K + i4);
    int e4 = (int)(i4 & 63);
    long r = i4 >> 6;
    int h = (int)(r & 7);
    long r2 = r >> 3;
    int t = (int)(r2 & 2047);
    int b = (int)(r2 >> 11);
    bf16x4 o;
    o[0] = f2bf(v[0]); o[1] = f2bf(v[1]); o[2] = f2bf(v[2]); o[3] = f2bf(v[3]);
    *(bf16x4*)(Kb + ((((long)b * NH + h) * NL + t) * NE + e4)) = o;
  } else if (bid < 5120) {
    const int vb = bid - 4096;
    const int b = vb >> 8;
    const int h = (vb >> 5) & 7;
    const int sb = (vb & 31) * 64;
    {
      const int s = tid >> 2, e0 = (tid & 3) * 16;
      const float* vp = V + ((((long)b * NS + sb + s) * NH + h) * NE + e0);
      #pragma unroll
      for (int j = 0; j < 4; ++j) {
        f32x4 u = *(const f32x4*)(vp + j * 4);
        #pragma unroll
        for (int r = 0; r < 4; ++r) t_lds[(e0 + j * 4 + r) * 65 + s] = f2bf(u[r]);
      }
    }
    __syncthreads();
    {
      const int e = tid >> 2, s0 = (tid & 3) * 16;
      short* op = Vt + (((long)b * NH + h) * NE + e) * NS + sb + s0;
      short tmp[16];
      #pragma unroll
      for (int j = 0; j < 16; ++j) tmp[j] = t_lds[e * 65 + s0 + j];
      *(bf16x8*)(op)     = *(bf16x8*)(tmp);
      *(bf16x8*)(op + 8) = *(bf16x8*)(tmp + 8);
    }
  } else {
    const long total = (long)NB * NL * NS;
    long g = (long)(bid - 5120) * 256 + tid;
    const long stride = 2048L * 256;
    for (; g < total; g += stride) {
      unsigned long long bal = __ballot(M[g] != 0);
      if ((tid & 63) == 0) Mb[g >> 6] = bal;
    }
  }
}

// ---------------- main kernel ----------------

// Stage a 64-row x 64-elem bf16 tile into LDS (2 gload_lds instrs / thread).
// Linear LDS dest; swizzle via pre-swizzled global source.
template<int RS>
static __device__ __forceinline__ void stage_tile(const short* __restrict__ base,
                                                  short* lds, int tid, int w) {
  #pragma unroll
  for (int c = 0; c < 2; ++c) {
    const int rr = (tid >> 3) + c * 32;
    const int gg = (tid & 7) ^ (rr & 7);
    const short* sp = base + (long)rr * RS + gg * 8;
    __builtin_amdgcn_global_load_lds(
        (const __attribute__((address_space(1))) void*)sp,
        (__attribute__((address_space(3))) void*)(void*)((char*)lds + c * 4096 + w * 1024),
        16, 0, 0);
  }
}

__global__ __launch_bounds__(256, 3)
void attn_main(const float* __restrict__ Qg, const short* __restrict__ Kb,
               const short* __restrict__ Vt, const unsigned long long* __restrict__ Mb,
               float* __restrict__ OutV, float* __restrict__ OutA)
{
  __shared__ short k_lds[2][SKC * 64];   // 16 KB
  __shared__ short vt_lds[2][NE * 64];   // 16 KB
  __shared__ float a_lds[4][16 * AW];    // 17 KB  -> ~50 KB total, 3 WGs/CU

  const int bid = blockIdx.x;
  const int hh = bid & 7, qt = (bid >> 3) & 31, bb = bid >> 8;
  const int tid = threadIdx.x, w = tid >> 6, lane = tid & 63;
  const int lq = lane & 15, lg = lane >> 4;
  const int qw = qt * 64 + w * 16, qrow = qw + lq;

  const short* Kpan = Kb + (long)(bb * NH + hh) * NS * NE;
  const short* Vpan = Vt + (long)(bb * NH + hh) * NE * NS;

  // Q fragments read fp32 -> bf16 in-kernel (Q layout [b][l][h][e])
  bf16x8 qf0, qf1;
  {
    const float* qp = Qg + (((long)bb * NL + qrow) * NH + hh) * NE + 8 * lg;
    qf0 = pack8(*(const f32x4*)(qp),      *(const f32x4*)(qp + 4));
    qf1 = pack8(*(const f32x4*)(qp + 32), *(const f32x4*)(qp + 36));
  }

  const unsigned long long* mrow = Mb + ((long)bb * NL + qrow) * (NS / 64);

  // ================ sweep 1: l = sum exp2 ================
  float l0 = 0.f, l1 = 0.f, l2 = 0.f, l3 = 0.f;
  {
    short *k0 = &k_lds[0][0], *k1 = &k_lds[1][0];
    stage_tile<NE>(Kpan, k0, tid, w);
    unsigned long long mcur = mrow[0];
    asm volatile("s_waitcnt vmcnt(0)" ::: "memory");
    __builtin_amdgcn_s_barrier();
    for (int t = 0; t < NT; ++t) {
      if (t + 1 < NT) stage_tile<NE>(Kpan + (long)(t + 1) * SKC * NE, k1, tid, w);
      __builtin_amdgcn_sched_barrier(0);   // pin stage ops oldest in vm queue
      const unsigned long long mnext = mrow[t + 1 < NT ? t + 1 : NT - 1];
      #pragma unroll
      for (int st = 0; st < SKC; st += 16) {
        const int krow = st + lq, sw = (krow & 7) << 3;
        const bf16x8 kf0 = *(const bf16x8*)&k0[(krow * 64 + 8 * lg) ^ sw];
        const bf16x8 kf1 = *(const bf16x8*)&k0[(krow * 64 + 32 + 8 * lg) ^ sw];
        f32x4 c = {0.f, 0.f, 0.f, 0.f};
        c = __builtin_amdgcn_mfma_f32_16x16x32_bf16(kf0, qf0, c, 0, 0, 0);
        c = __builtin_amdgcn_mfma_f32_16x16x32_bf16(kf1, qf1, c, 0, 0, 0);
        const unsigned mb4 = (unsigned)(mcur >> (st + 4 * lg)) & 0xFu;
        l0 += (mb4 & 1u) ? 0.f : EXP2(fmaf(c[0], SC2, MB2));
        l1 += (mb4 & 2u) ? 0.f : EXP2(fmaf(c[1], SC2, MB2));
        l2 += (mb4 & 4u) ? 0.f : EXP2(fmaf(c[2], SC2, MB2));
        l3 += (mb4 & 8u) ? 0.f : EXP2(fmaf(c[3], SC2, MB2));
      }
      mcur = mnext;
      if (t + 1 < NT)
        asm volatile("s_waitcnt vmcnt(1)" ::: "memory");   // drain stage; exempt mask
      __builtin_amdgcn_s_barrier();
      short* tk = k0; k0 = k1; k1 = tk;
    }
  }
  float l = (l0 + l1) + (l2 + l3);
  l += __shfl_xor(l, 16, 64);
  l += __shfl_xor(l, 32, 64);
  const float rinv = 1.0f / l;

  // ================ sweep 2: A (cached full-line stores) + PV ================
  f32x4 accv[4];
  #pragma unroll
  for (int et = 0; et < 4; ++et) accv[et] = (f32x4){0.f, 0.f, 0.f, 0.f};

  float* abase = OutA + ((long)(bb * NH + hh) * NL + qw) * NS;   // row 0 of wave tile
  {
    short *k0 = &k_lds[0][0], *k1 = &k_lds[1][0];
    short *v0 = &vt_lds[0][0], *v1 = &vt_lds[1][0];
    stage_tile<NE>(Kpan, k0, tid, w);
    stage_tile<NS>(Vpan, v0, tid, w);
    unsigned long long mcur = mrow[0];
    asm volatile("s_waitcnt vmcnt(0)" ::: "memory");
    __builtin_amdgcn_s_barrier();
    for (int t = 0; t < NT; ++t) {
      const int sb = t * SKC;
      if (t + 1 < NT) {
        stage_tile<NE>(Kpan + (long)(t + 1) * SKC * NE, k1, tid, w);
        stage_tile<NS>(Vpan + (t + 1) * SKC, v1, tid, w);
      }
      __builtin_amdgcn_sched_barrier(0);   // pin stage ops oldest in vm queue
      const unsigned long long mnext = mrow[t + 1 < NT ? t + 1 : NT - 1];
      #pragma unroll
      for (int st = 0; st < SKC; st += 16) {
        const int krow = st + lq, sw = (krow & 7) << 3;
        const bf16x8 kf0 = *(const bf16x8*)&k0[(krow * 64 + 8 * lg) ^ sw];
        const bf16x8 kf1 = *(const bf16x8*)&k0[(krow * 64 + 32 + 8 * lg) ^ sw];
        f32x4 c = {0.f, 0.f, 0.f, 0.f};
        c = __builtin_amdgcn_mfma_f32_16x16x32_bf16(kf0, qf0, c, 0, 0, 0);
        c = __builtin_amdgcn_mfma_f32_16x16x32_bf16(kf1, qf1, c, 0, 0, 0);
        const unsigned mb4 = (unsigned)(mcur >> (st + 4 * lg)) & 0xFu;
        f32x4 av;
        av[0] = (mb4 & 1u) ? 0.f : EXP2(fmaf(c[0], SC2, MB2)) * rinv;
        av[1] = (mb4 & 2u) ? 0.f : EXP2(fmaf(c[1], SC2, MB2)) * rinv;
        av[2] = (mb4 & 4u) ? 0.f : EXP2(fmaf(c[2], SC2, MB2)) * rinv;
        av[3] = (mb4 & 8u) ? 0.f : EXP2(fmaf(c[3], SC2, MB2)) * rinv;
        *(f32x4*)&a_lds[w][lq * AW + st + 4 * lg] = av;   // row = lq (normalized A)
      }
      // flush A tile with PLAIN cached stores (L2 write-back path):
      // each instruction = 4 rows x 256B contiguous (full lines)
      {
        const int rr = lane >> 4, ls = lane & 15;
        #pragma unroll
        for (int it = 0; it < 4; ++it) {
          const int r = it * 4 + rr;
          const f32x4 a4 = *(const f32x4*)&a_lds[w][r * AW + ls * 4];
          *(f32x4*)(abase + (long)r * NS + sb + ls * 4) = a4;
        }
      }
      // PV over this 64-s chunk; P read back from a_lds (already normalized)
      #pragma unroll
      for (int kc2 = 0; kc2 < 2; ++kc2) {
        const f32x4 u0 = *(const f32x4*)&a_lds[w][lq * AW + kc2 * 32 + 8 * lg];
        const f32x4 u1 = *(const f32x4*)&a_lds[w][lq * AW + kc2 * 32 + 8 * lg + 4];
        const bf16x8 pf = pack8(u0, u1);
        #pragma unroll
        for (int et = 0; et < 4; ++et) {
          const int er = et * 16 + lq;
          const bf16x8 vf = *(const bf16x8*)&v0[(er * 64 + kc2 * 32 + 8 * lg) ^ ((er & 7) << 3)];
          accv[et] = __builtin_amdgcn_mfma_f32_16x16x32_bf16(pf, vf, accv[et], 0, 0, 0);
        }
      }
      mcur = mnext;
      if (t + 1 < NT)
        asm volatile("s_waitcnt vmcnt(5)" ::: "memory");   // drain stage; exempt mask + 4 stores
      __builtin_amdgcn_s_barrier();
      short* tk = k0; k0 = k1; k1 = tk;
      short* tv = v0; v0 = v1; v1 = tv;
    }
  }

  // write V: lane holds out[q = qw + 4*lg + r][e = et*16 + lq] (P normalized)
  {
    float* vout = OutV + (((long)bb * NL + qw + 4 * lg) * NH + hh) * NE + lq;
    #pragma unroll
    for (int r = 0; r < 4; ++r)
      #pragma unroll
      for (int et = 0; et < 4; ++et)
        vout[(long)r * (NH * NE) + et * 16] = accv[et][r];
  }
}

extern "C" void kernel_launch(void* const* d_in, const int* in_sizes, int n_in,
                              void* d_out, int out_size, void* d_ws, size_t ws_size,
                              hipStream_t stream) {
  const float* Q = (const float*)d_in[0];
  const float* K = (const float*)d_in[1];
  const float* V = (const float*)d_in[2];
  const int*   M = (const int*)d_in[3];
  float* outv = (float*)d_out;
  float* outa = outv + (size_t)NB * NL * NH * NE;

  const size_t NQK = (size_t)NB * NH * NL * NE;
  short* Kbw = (short*)d_ws;
  short* Vtw = Kbw + NQK;
  unsigned long long* Mbp = (unsigned long long*)(Vtw + NQK);

  prep_all<<<dim3(7168), 256, 0, stream>>>(K, V, M, Kbw, Vtw, Mbp);
  attn_main<<<dim3(NB * (NL / 64) * NH), 256, 0, stream>>>(Q, Kbw, Vtw, Mbp, outv, outa);
}

// Round 20
// 192.115 us; speedup vs baseline: 1.4024x; 1.4024x over previous
//
#include <hip/hip_runtime.h>

// ---------------------------------------------------------------------------
// Fused full attention (V, A). B=4 L=S=2048 H=8 E=64, fp32 in/out.
// r14 base (190.9us x2) with ONE change: A-flush stores emitted as inline-asm
//   global_store_dwordx4 ... nt sc0 sc1   (true streaming / no-L2-allocate).
// Theory: __builtin_nontemporal_store emits only `nt` which still
// WRITE-ALLOCATES in L2 -> the persistent ~537MB FETCH (=A size) seen in r3
// and r13 is allocation-fetch for the store stream. sc0+sc1 (system scope)
// forces no-allocate write-through on gfx940+ -> fetch should vanish.
// r18 (cached stores, 269us) showed store policy is first-order here.
// Everything else byte-identical to r14: 1 tile/WG, grid 1024, two sweeps,
// K/V gload_lds dbuf staging, counted vmcnt, a_lds full-line flush.
// ---------------------------------------------------------------------------

typedef __attribute__((ext_vector_type(8))) short bf16x8;
typedef __attribute__((ext_vector_type(4))) short bf16x4;
typedef __attribute__((ext_vector_type(4))) float f32x4;

#define NB 4
#define NL 2048
#define NS 2048
#define NH 8
#define NE 64
#define SKC 64
#define NT (NS / SKC)
#define AW 68   // padded a_lds row stride (floats)
// exp(s*0.125 - 4) == exp2(s*SC2 + MB2)
#define SC2 0.18033688011112042f
#define MB2 -5.770780163555854f
#define EXP2(x) __builtin_amdgcn_exp2f(x)

static __device__ __forceinline__ short f2bf(float x) {
  unsigned u = __builtin_bit_cast(unsigned, x);
  u += 0x7fffu + ((u >> 16) & 1u);   // round-to-nearest-even
  return (short)(u >> 16);
}

static __device__ __forceinline__ bf16x8 pack8(f32x4 a, f32x4 b) {
  bf16x8 t;
  t[0] = f2bf(a[0]); t[1] = f2bf(a[1]); t[2] = f2bf(a[2]); t[3] = f2bf(a[3]);
  t[4] = f2bf(b[0]); t[5] = f2bf(b[1]); t[6] = f2bf(b[2]); t[7] = f2bf(b[3]);
  return t;
}

// streaming store: no-allocate write-through (nt + system-scope sc0 sc1)
static __device__ __forceinline__ void stream_store(float* p, f32x4 v) {
  asm volatile("global_store_dwordx4 %0, %1, off nt sc0 sc1"
               :: "v"(p), "v"(v) : "memory");
}

// ---------------- merged prep kernel ----------------
__global__ __launch_bounds__(256)
void prep_all(const float* __restrict__ K, const float* __restrict__ V,
              const int* __restrict__ M, short* __restrict__ Kb,
              short* __restrict__ Vt, unsigned long long* __restrict__ Mb) {
  __shared__ short t_lds[64 * 65];
  const int bid = blockIdx.x, tid = threadIdx.x;
  if (bid < 4096) {
    long i4 = ((long)bid * 256 + tid) * 4;
    f32x4 v = *(const f32x4*)(K + i4);
    int e4 = (int)(i4 & 63);
    long r = i4 >> 6;
    int h = (int)(r & 7);
    long r2 = r >> 3;
    int t = (int)(r2 & 2047);
    int b = (int)(r2 >> 11);
    bf16x4 o;
    o[0] = f2bf(v[0]); o[1] = f2bf(v[1]); o[2] = f2bf(v[2]); o[3] = f2bf(v[3]);
    *(bf16x4*)(Kb + ((((long)b * NH + h) * NL + t) * NE + e4)) = o;
  } else if (bid < 5120) {
    const int vb = bid - 4096;
    const int b = vb >> 8;
    const int h = (vb >> 5) & 7;
    const int sb = (vb & 31) * 64;
    {
      const int s = tid >> 2, e0 = (tid & 3) * 16;
      const float* vp = V + ((((long)b * NS + sb + s) * NH + h) * NE + e0);
      #pragma unroll
      for (int j = 0; j < 4; ++j) {
        f32x4 u = *(const f32x4*)(vp + j * 4);
        #pragma unroll
        for (int r = 0; r < 4; ++r) t_lds[(e0 + j * 4 + r) * 65 + s] = f2bf(u[r]);
      }
    }
    __syncthreads();
    {
      const int e = tid >> 2, s0 = (tid & 3) * 16;
      short* op = Vt + (((long)b * NH + h) * NE + e) * NS + sb + s0;
      short tmp[16];
      #pragma unroll
      for (int j = 0; j < 16; ++j) tmp[j] = t_lds[e * 65 + s0 + j];
      *(bf16x8*)(op)     = *(bf16x8*)(tmp);
      *(bf16x8*)(op + 8) = *(bf16x8*)(tmp + 8);
    }
  } else {
    const long total = (long)NB * NL * NS;
    long g = (long)(bid - 5120) * 256 + tid;
    const long stride = 2048L * 256;
    for (; g < total; g += stride) {
      unsigned long long bal = __ballot(M[g] != 0);
      if ((tid & 63) == 0) Mb[g >> 6] = bal;
    }
  }
}

// ---------------- main kernel ----------------

// Stage a 64-row x 64-elem bf16 tile into LDS (2 gload_lds instrs / thread).
// Linear LDS dest; swizzle via pre-swizzled global source.
template<int RS>
static __device__ __forceinline__ void stage_tile(const short* __restrict__ base,
                                                  short* lds, int tid, int w) {
  #pragma unroll
  for (int c = 0; c < 2; ++c) {
    const int rr = (tid >> 3) + c * 32;
    const int gg = (tid & 7) ^ (rr & 7);
    const short* sp = base + (long)rr * RS + gg * 8;
    __builtin_amdgcn_global_load_lds(
        (const __attribute__((address_space(1))) void*)sp,
        (__attribute__((address_space(3))) void*)(void*)((char*)lds + c * 4096 + w * 1024),
        16, 0, 0);
  }
}

__global__ __launch_bounds__(256, 3)
void attn_main(const float* __restrict__ Qg, const short* __restrict__ Kb,
               const short* __restrict__ Vt, const unsigned long long* __restrict__ Mb,
               float* __restrict__ OutV, float* __restrict__ OutA)
{
  __shared__ short k_lds[2][SKC * 64];   // 16 KB
  __shared__ short vt_lds[2][NE * 64];   // 16 KB
  __shared__ float a_lds[4][16 * AW];    // 17 KB  -> ~50 KB total, 3 WGs/CU

  const int bid = blockIdx.x;
  const int hh = bid & 7, qt = (bid >> 3) & 31, bb = bid >> 8;
  const int tid = threadIdx.x, w = tid >> 6, lane = tid & 63;
  const int lq = lane & 15, lg = lane >> 4;
  const int qw = qt * 64 + w * 16, qrow = qw + lq;

  const short* Kpan = Kb + (long)(bb * NH + hh) * NS * NE;
  const short* Vpan = Vt + (long)(bb * NH + hh) * NE * NS;

  // Q fragments read fp32 -> bf16 in-kernel (Q layout [b][l][h][e])
  bf16x8 qf0, qf1;
  {
    const float* qp = Qg + (((long)bb * NL + qrow) * NH + hh) * NE + 8 * lg;
    qf0 = pack8(*(const f32x4*)(qp),      *(const f32x4*)(qp + 4));
    qf1 = pack8(*(const f32x4*)(qp + 32), *(const f32x4*)(qp + 36));
  }

  const unsigned long long* mrow = Mb + ((long)bb * NL + qrow) * (NS / 64);

  // ================ sweep 1: l = sum exp2 ================
  float l0 = 0.f, l1 = 0.f, l2 = 0.f, l3 = 0.f;
  {
    short *k0 = &k_lds[0][0], *k1 = &k_lds[1][0];
    stage_tile<NE>(Kpan, k0, tid, w);
    unsigned long long mcur = mrow[0];
    asm volatile("s_waitcnt vmcnt(0)" ::: "memory");
    __builtin_amdgcn_s_barrier();
    for (int t = 0; t < NT; ++t) {
      if (t + 1 < NT) stage_tile<NE>(Kpan + (long)(t + 1) * SKC * NE, k1, tid, w);
      __builtin_amdgcn_sched_barrier(0);   // pin stage ops oldest in vm queue
      const unsigned long long mnext = mrow[t + 1 < NT ? t + 1 : NT - 1];
      #pragma unroll
      for (int st = 0; st < SKC; st += 16) {
        const int krow = st + lq, sw = (krow & 7) << 3;
        const bf16x8 kf0 = *(const bf16x8*)&k0[(krow * 64 + 8 * lg) ^ sw];
        const bf16x8 kf1 = *(const bf16x8*)&k0[(krow * 64 + 32 + 8 * lg) ^ sw];
        f32x4 c = {0.f, 0.f, 0.f, 0.f};
        c = __builtin_amdgcn_mfma_f32_16x16x32_bf16(kf0, qf0, c, 0, 0, 0);
        c = __builtin_amdgcn_mfma_f32_16x16x32_bf16(kf1, qf1, c, 0, 0, 0);
        const unsigned mb4 = (unsigned)(mcur >> (st + 4 * lg)) & 0xFu;
        l0 += (mb4 & 1u) ? 0.f : EXP2(fmaf(c[0], SC2, MB2));
        l1 += (mb4 & 2u) ? 0.f : EXP2(fmaf(c[1], SC2, MB2));
        l2 += (mb4 & 4u) ? 0.f : EXP2(fmaf(c[2], SC2, MB2));
        l3 += (mb4 & 8u) ? 0.f : EXP2(fmaf(c[3], SC2, MB2));
      }
      mcur = mnext;
      if (t + 1 < NT)
        asm volatile("s_waitcnt vmcnt(1)" ::: "memory");   // drain stage; exempt mask
      __builtin_amdgcn_s_barrier();
      short* tk = k0; k0 = k1; k1 = tk;
    }
  }
  float l = (l0 + l1) + (l2 + l3);
  l += __shfl_xor(l, 16, 64);
  l += __shfl_xor(l, 32, 64);
  const float rinv = 1.0f / l;

  // ================ sweep 2: A (streaming full-line stores) + PV ================
  f32x4 accv[4];
  #pragma unroll
  for (int et = 0; et < 4; ++et) accv[et] = (f32x4){0.f, 0.f, 0.f, 0.f};

  float* abase = OutA + ((long)(bb * NH + hh) * NL + qw) * NS;   // row 0 of wave tile
  {
    short *k0 = &k_lds[0][0], *k1 = &k_lds[1][0];
    short *v0 = &vt_lds[0][0], *v1 = &vt_lds[1][0];
    stage_tile<NE>(Kpan, k0, tid, w);
    stage_tile<NS>(Vpan, v0, tid, w);
    unsigned long long mcur = mrow[0];
    asm volatile("s_waitcnt vmcnt(0)" ::: "memory");
    __builtin_amdgcn_s_barrier();
    for (int t = 0; t < NT; ++t) {
      const int sb = t * SKC;
      if (t + 1 < NT) {
        stage_tile<NE>(Kpan + (long)(t + 1) * SKC * NE, k1, tid, w);
        stage_tile<NS>(Vpan + (t + 1) * SKC, v1, tid, w);
      }
      __builtin_amdgcn_sched_barrier(0);   // pin stage ops oldest in vm queue
      const unsigned long long mnext = mrow[t + 1 < NT ? t + 1 : NT - 1];
      #pragma unroll
      for (int st = 0; st < SKC; st += 16) {
        const int krow = st + lq, sw = (krow & 7) << 3;
        const bf16x8 kf0 = *(const bf16x8*)&k0[(krow * 64 + 8 * lg) ^ sw];
        const bf16x8 kf1 = *(const bf16x8*)&k0[(krow * 64 + 32 + 8 * lg) ^ sw];
        f32x4 c = {0.f, 0.f, 0.f, 0.f};
        c = __builtin_amdgcn_mfma_f32_16x16x32_bf16(kf0, qf0, c, 0, 0, 0);
        c = __builtin_amdgcn_mfma_f32_16x16x32_bf16(kf1, qf1, c, 0, 0, 0);
        const unsigned mb4 = (unsigned)(mcur >> (st + 4 * lg)) & 0xFu;
        f32x4 av;
        av[0] = (mb4 & 1u) ? 0.f : EXP2(fmaf(c[0], SC2, MB2)) * rinv;
        av[1] = (mb4 & 2u) ? 0.f : EXP2(fmaf(c[1], SC2, MB2)) * rinv;
        av[2] = (mb4 & 4u) ? 0.f : EXP2(fmaf(c[2], SC2, MB2)) * rinv;
        av[3] = (mb4 & 8u) ? 0.f : EXP2(fmaf(c[3], SC2, MB2)) * rinv;
        *(f32x4*)&a_lds[w][lq * AW + st + 4 * lg] = av;   // row = lq (normalized A)
      }
      // flush A tile with STREAMING stores (nt sc0 sc1 = no L2 allocate):
      // each instruction = 4 rows x 256B contiguous (full 128B lines)
      {
        const int rr = lane >> 4, ls = lane & 15;
        #pragma unroll
        for (int it = 0; it < 4; ++it) {
          const int r = it * 4 + rr;
          const f32x4 a4 = *(const f32x4*)&a_lds[w][r * AW + ls * 4];
          stream_store(abase + (long)r * NS + sb + ls * 4, a4);
        }
      }
      // PV over this 64-s chunk; P read back from a_lds (already normalized)
      #pragma unroll
      for (int kc2 = 0; kc2 < 2; ++kc2) {
        const f32x4 u0 = *(const f32x4*)&a_lds[w][lq * AW + kc2 * 32 + 8 * lg];
        const f32x4 u1 = *(const f32x4*)&a_lds[w][lq * AW + kc2 * 32 + 8 * lg + 4];
        const bf16x8 pf = pack8(u0, u1);
        #pragma unroll
        for (int et = 0; et < 4; ++et) {
          const int er = et * 16 + lq;
          const bf16x8 vf = *(const bf16x8*)&v0[(er * 64 + kc2 * 32 + 8 * lg) ^ ((er & 7) << 3)];
          accv[et] = __builtin_amdgcn_mfma_f32_16x16x32_bf16(pf, vf, accv[et], 0, 0, 0);
        }
      }
      mcur = mnext;
      if (t + 1 < NT)
        asm volatile("s_waitcnt vmcnt(5)" ::: "memory");   // drain stage; exempt mask + 4 stores
      __builtin_amdgcn_s_barrier();
      short* tk = k0; k0 = k1; k1 = tk;
      short* tv = v0; v0 = v1; v1 = tv;
    }
    // ensure asm stores are drained before kernel end (compiler can't see them)
    asm volatile("s_waitcnt vmcnt(0)" ::: "memory");
  }

  // write V: lane holds out[q = qw + 4*lg + r][e = et*16 + lq] (P normalized)
  {
    float* vout = OutV + (((long)bb * NL + qw + 4 * lg) * NH + hh) * NE + lq;
    #pragma unroll
    for (int r = 0; r < 4; ++r)
      #pragma unroll
      for (int et = 0; et < 4; ++et)
        vout[(long)r * (NH * NE) + et * 16] = accv[et][r];
  }
}

extern "C" void kernel_launch(void* const* d_in, const int* in_sizes, int n_in,
                              void* d_out, int out_size, void* d_ws, size_t ws_size,
                              hipStream_t stream) {
  const float* Q = (const float*)d_in[0];
  const float* K = (const float*)d_in[1];
  const float* V = (const float*)d_in[2];
  const int*   M = (const int*)d_in[3];
  float* outv = (float*)d_out;
  float* outa = outv + (size_t)NB * NL * NH * NE;

  const size_t NQK = (size_t)NB * NH * NL * NE;
  short* Kbw = (short*)d_ws;
  short* Vtw = Kbw + NQK;
  unsigned long long* Mbp = (unsigned long long*)(Vtw + NQK);

  prep_all<<<dim3(7168), 256, 0, stream>>>(K, V, M, Kbw, Vtw, Mbp);
  attn_main<<<dim3(NB * (NL / 64) * NH), 256, 0, stream>>>(Q, Kbw, Vtw, Mbp, outv, outa);
}

// Round 21
// 171.315 us; speedup vs baseline: 1.5726x; 1.1214x over previous
//
#include <hip/hip_runtime.h>

// ---------------------------------------------------------------------------
// Fused full attention (V, A). B=4 L=S=2048 H=8 E=64, fp32 in/out.
// r14 structure with REGISTER-STAGED prefetch replacing global_load_lds.
// Evidence (r9 vs r3/r13 FETCH): global_load_lds traffic is NOT absorbed by
// L2/LLC -> ~600MB/dispatch parasitic HBM fetch (K staged 2x + V 1x per WG).
// Vector loads DO hit L2 (r9: FETCH=39MB). So: load next chunk into REGISTERS
// at top of iter (latency hidden under body), ds_write to LDS at bottom,
// __syncthreads. Plain-HIP sync (no inline-asm vmcnt) — compiler inserts
// exact waitcnts; removes the r15/r16 race class entirely.
//   sweep1: l = sum exp2(s*SC2+MB2)     [K dbuf]
//   sweep2: A = p*rinv -> a_lds -> full-line nt stores; PV from vt dbuf
// ---------------------------------------------------------------------------

typedef __attribute__((ext_vector_type(8))) short bf16x8;
typedef __attribute__((ext_vector_type(4))) short bf16x4;
typedef __attribute__((ext_vector_type(4))) float f32x4;

#define NB 4
#define NL 2048
#define NS 2048
#define NH 8
#define NE 64
#define SKC 64
#define NT (NS / SKC)
#define AW 68   // padded a_lds row stride (floats)
// exp(s*0.125 - 4) == exp2(s*SC2 + MB2)
#define SC2 0.18033688011112042f
#define MB2 -5.770780163555854f
#define EXP2(x) __builtin_amdgcn_exp2f(x)

static __device__ __forceinline__ short f2bf(float x) {
  unsigned u = __builtin_bit_cast(unsigned, x);
  u += 0x7fffu + ((u >> 16) & 1u);   // round-to-nearest-even
  return (short)(u >> 16);
}

static __device__ __forceinline__ bf16x8 pack8(f32x4 a, f32x4 b) {
  bf16x8 t;
  t[0] = f2bf(a[0]); t[1] = f2bf(a[1]); t[2] = f2bf(a[2]); t[3] = f2bf(a[3]);
  t[4] = f2bf(b[0]); t[5] = f2bf(b[1]); t[6] = f2bf(b[2]); t[7] = f2bf(b[3]);
  return t;
}

// ---------------- merged prep kernel ----------------
__global__ __launch_bounds__(256)
void prep_all(const float* __restrict__ K, const float* __restrict__ V,
              const int* __restrict__ M, short* __restrict__ Kb,
              short* __restrict__ Vt, unsigned long long* __restrict__ Mb) {
  __shared__ short t_lds[64 * 65];
  const int bid = blockIdx.x, tid = threadIdx.x;
  if (bid < 4096) {
    long i4 = ((long)bid * 256 + tid) * 4;
    f32x4 v = *(const f32x4*)(K + i4);
    int e4 = (int)(i4 & 63);
    long r = i4 >> 6;
    int h = (int)(r & 7);
    long r2 = r >> 3;
    int t = (int)(r2 & 2047);
    int b = (int)(r2 >> 11);
    bf16x4 o;
    o[0] = f2bf(v[0]); o[1] = f2bf(v[1]); o[2] = f2bf(v[2]); o[3] = f2bf(v[3]);
    *(bf16x4*)(Kb + ((((long)b * NH + h) * NL + t) * NE + e4)) = o;
  } else if (bid < 5120) {
    const int vb = bid - 4096;
    const int b = vb >> 8;
    const int h = (vb >> 5) & 7;
    const int sb = (vb & 31) * 64;
    {
      const int s = tid >> 2, e0 = (tid & 3) * 16;
      const float* vp = V + ((((long)b * NS + sb + s) * NH + h) * NE + e0);
      #pragma unroll
      for (int j = 0; j < 4; ++j) {
        f32x4 u = *(const f32x4*)(vp + j * 4);
        #pragma unroll
        for (int r = 0; r < 4; ++r) t_lds[(e0 + j * 4 + r) * 65 + s] = f2bf(u[r]);
      }
    }
    __syncthreads();
    {
      const int e = tid >> 2, s0 = (tid & 3) * 16;
      short* op = Vt + (((long)b * NH + h) * NE + e) * NS + sb + s0;
      short tmp[16];
      #pragma unroll
      for (int j = 0; j < 16; ++j) tmp[j] = t_lds[e * 65 + s0 + j];
      *(bf16x8*)(op)     = *(bf16x8*)(tmp);
      *(bf16x8*)(op + 8) = *(bf16x8*)(tmp + 8);
    }
  } else {
    const long total = (long)NB * NL * NS;
    long g = (long)(bid - 5120) * 256 + tid;
    const long stride = 2048L * 256;
    for (; g < total; g += stride) {
      unsigned long long bal = __ballot(M[g] != 0);
      if ((tid & 63) == 0) Mb[g >> 6] = bal;
    }
  }
}

// ---------------- main kernel ----------------

// Register-staged tile prefetch: load 2x16B per thread (pre-swizzled source,
// same addresses gload_lds used), write later to the linear LDS layout
// (byte offset c*4096 + tid*16 — identical to what gload_lds produced).
template<int RS>
static __device__ __forceinline__ void stage_load(const short* __restrict__ base,
                                                  int tid, bf16x8& r0, bf16x8& r1) {
  {
    const int rr = (tid >> 3);
    const int gg = (tid & 7) ^ (rr & 7);
    r0 = *(const bf16x8*)(base + (long)rr * RS + gg * 8);
  }
  {
    const int rr = (tid >> 3) + 32;
    const int gg = (tid & 7) ^ (rr & 7);
    r1 = *(const bf16x8*)(base + (long)rr * RS + gg * 8);
  }
}

static __device__ __forceinline__ void stage_write(short* lds, int tid,
                                                   bf16x8 r0, bf16x8 r1) {
  *(bf16x8*)(lds + tid * 8)        = r0;   // c=0 half: bytes [0,4096)
  *(bf16x8*)(lds + 2048 + tid * 8) = r1;   // c=1 half: bytes [4096,8192)
}

__global__ __launch_bounds__(256, 3)
void attn_main(const float* __restrict__ Qg, const short* __restrict__ Kb,
               const short* __restrict__ Vt, const unsigned long long* __restrict__ Mb,
               float* __restrict__ OutV, float* __restrict__ OutA)
{
  __shared__ short k_lds[2][SKC * 64];   // 16 KB
  __shared__ short vt_lds[2][NE * 64];   // 16 KB
  __shared__ float a_lds[4][16 * AW];    // 17 KB  -> ~50 KB total, 3 WGs/CU

  const int bid = blockIdx.x;
  const int hh = bid & 7, qt = (bid >> 3) & 31, bb = bid >> 8;
  const int tid = threadIdx.x, w = tid >> 6, lane = tid & 63;
  const int lq = lane & 15, lg = lane >> 4;
  const int qw = qt * 64 + w * 16, qrow = qw + lq;

  const short* Kpan = Kb + (long)(bb * NH + hh) * NS * NE;
  const short* Vpan = Vt + (long)(bb * NH + hh) * NE * NS;

  // Q fragments read fp32 -> bf16 in-kernel (Q layout [b][l][h][e])
  bf16x8 qf0, qf1;
  {
    const float* qp = Qg + (((long)bb * NL + qrow) * NH + hh) * NE + 8 * lg;
    qf0 = pack8(*(const f32x4*)(qp),      *(const f32x4*)(qp + 4));
    qf1 = pack8(*(const f32x4*)(qp + 32), *(const f32x4*)(qp + 36));
  }

  const unsigned long long* mrow = Mb + ((long)bb * NL + qrow) * (NS / 64);

  // ================ sweep 1: l = sum exp2 ================
  float l0 = 0.f, l1 = 0.f, l2 = 0.f, l3 = 0.f;
  {
    short *k0 = &k_lds[0][0], *k1 = &k_lds[1][0];
    {
      bf16x8 p0, p1;
      stage_load<NE>(Kpan, tid, p0, p1);
      stage_write(k0, tid, p0, p1);
    }
    unsigned long long mcur = mrow[0];
    __syncthreads();
    for (int t = 0; t < NT; ++t) {
      const int tn = t + 1 < NT ? t + 1 : t;
      bf16x8 n0, n1;
      stage_load<NE>(Kpan + (long)tn * SKC * NE, tid, n0, n1);   // issue-early
      const unsigned long long mnext = mrow[t + 1 < NT ? t + 1 : NT - 1];
      #pragma unroll
      for (int st = 0; st < SKC; st += 16) {
        const int krow = st + lq, sw = (krow & 7) << 3;
        const bf16x8 kf0 = *(const bf16x8*)&k0[(krow * 64 + 8 * lg) ^ sw];
        const bf16x8 kf1 = *(const bf16x8*)&k0[(krow * 64 + 32 + 8 * lg) ^ sw];
        f32x4 c = {0.f, 0.f, 0.f, 0.f};
        c = __builtin_amdgcn_mfma_f32_16x16x32_bf16(kf0, qf0, c, 0, 0, 0);
        c = __builtin_amdgcn_mfma_f32_16x16x32_bf16(kf1, qf1, c, 0, 0, 0);
        const unsigned mb4 = (unsigned)(mcur >> (st + 4 * lg)) & 0xFu;
        l0 += (mb4 & 1u) ? 0.f : EXP2(fmaf(c[0], SC2, MB2));
        l1 += (mb4 & 2u) ? 0.f : EXP2(fmaf(c[1], SC2, MB2));
        l2 += (mb4 & 4u) ? 0.f : EXP2(fmaf(c[2], SC2, MB2));
        l3 += (mb4 & 8u) ? 0.f : EXP2(fmaf(c[3], SC2, MB2));
      }
      mcur = mnext;
      if (t + 1 < NT) stage_write(k1, tid, n0, n1);   // write-late
      __syncthreads();
      short* tk = k0; k0 = k1; k1 = tk;
    }
  }
  float l = (l0 + l1) + (l2 + l3);
  l += __shfl_xor(l, 16, 64);
  l += __shfl_xor(l, 32, 64);
  const float rinv = 1.0f / l;

  // ================ sweep 2: A (full-line nt stores) + PV ================
  f32x4 accv[4];
  #pragma unroll
  for (int et = 0; et < 4; ++et) accv[et] = (f32x4){0.f, 0.f, 0.f, 0.f};

  float* abase = OutA + ((long)(bb * NH + hh) * NL + qw) * NS;   // row 0 of wave tile
  {
    short *k0 = &k_lds[0][0], *k1 = &k_lds[1][0];
    short *v0 = &vt_lds[0][0], *v1 = &vt_lds[1][0];
    {
      bf16x8 p0, p1, p2, p3;
      stage_load<NE>(Kpan, tid, p0, p1);
      stage_load<NS>(Vpan, tid, p2, p3);
      stage_write(k0, tid, p0, p1);
      stage_write(v0, tid, p2, p3);
    }
    unsigned long long mcur = mrow[0];
    __syncthreads();
    for (int t = 0; t < NT; ++t) {
      const int sb = t * SKC;
      const int tn = t + 1 < NT ? t + 1 : t;
      bf16x8 kn0, kn1, vn0, vn1;
      stage_load<NE>(Kpan + (long)tn * SKC * NE, tid, kn0, kn1);   // issue-early
      stage_load<NS>(Vpan + tn * SKC, tid, vn0, vn1);
      const unsigned long long mnext = mrow[t + 1 < NT ? t + 1 : NT - 1];
      #pragma unroll
      for (int st = 0; st < SKC; st += 16) {
        const int krow = st + lq, sw = (krow & 7) << 3;
        const bf16x8 kf0 = *(const bf16x8*)&k0[(krow * 64 + 8 * lg) ^ sw];
        const bf16x8 kf1 = *(const bf16x8*)&k0[(krow * 64 + 32 + 8 * lg) ^ sw];
        f32x4 c = {0.f, 0.f, 0.f, 0.f};
        c = __builtin_amdgcn_mfma_f32_16x16x32_bf16(kf0, qf0, c, 0, 0, 0);
        c = __builtin_amdgcn_mfma_f32_16x16x32_bf16(kf1, qf1, c, 0, 0, 0);
        const unsigned mb4 = (unsigned)(mcur >> (st + 4 * lg)) & 0xFu;
        f32x4 av;
        av[0] = (mb4 & 1u) ? 0.f : EXP2(fmaf(c[0], SC2, MB2)) * rinv;
        av[1] = (mb4 & 2u) ? 0.f : EXP2(fmaf(c[1], SC2, MB2)) * rinv;
        av[2] = (mb4 & 4u) ? 0.f : EXP2(fmaf(c[2], SC2, MB2)) * rinv;
        av[3] = (mb4 & 8u) ? 0.f : EXP2(fmaf(c[3], SC2, MB2)) * rinv;
        *(f32x4*)&a_lds[w][lq * AW + st + 4 * lg] = av;   // row = lq (normalized A)
      }
      // flush A tile: each instruction = 4 rows x 256B contiguous (full lines)
      {
        const int rr = lane >> 4, ls = lane & 15;
        #pragma unroll
        for (int it = 0; it < 4; ++it) {
          const int r = it * 4 + rr;
          const f32x4 a4 = *(const f32x4*)&a_lds[w][r * AW + ls * 4];
          __builtin_nontemporal_store(a4, (f32x4*)(abase + (long)r * NS + sb + ls * 4));
        }
      }
      // PV over this 64-s chunk; P read back from a_lds (already normalized)
      #pragma unroll
      for (int kc2 = 0; kc2 < 2; ++kc2) {
        const f32x4 u0 = *(const f32x4*)&a_lds[w][lq * AW + kc2 * 32 + 8 * lg];
        const f32x4 u1 = *(const f32x4*)&a_lds[w][lq * AW + kc2 * 32 + 8 * lg + 4];
        const bf16x8 pf = pack8(u0, u1);
        #pragma unroll
        for (int et = 0; et < 4; ++et) {
          const int er = et * 16 + lq;
          const bf16x8 vf = *(const bf16x8*)&v0[(er * 64 + kc2 * 32 + 8 * lg) ^ ((er & 7) << 3)];
          accv[et] = __builtin_amdgcn_mfma_f32_16x16x32_bf16(pf, vf, accv[et], 0, 0, 0);
        }
      }
      mcur = mnext;
      if (t + 1 < NT) {
        stage_write(k1, tid, kn0, kn1);   // write-late
        stage_write(v1, tid, vn0, vn1);
      }
      __syncthreads();
      short* tk = k0; k0 = k1; k1 = tk;
      short* tv = v0; v0 = v1; v1 = tv;
    }
  }

  // write V: lane holds out[q = qw + 4*lg + r][e = et*16 + lq] (P normalized)
  {
    float* vout = OutV + (((long)bb * NL + qw + 4 * lg) * NH + hh) * NE + lq;
    #pragma unroll
    for (int r = 0; r < 4; ++r)
      #pragma unroll
      for (int et = 0; et < 4; ++et)
        vout[(long)r * (NH * NE) + et * 16] = accv[et][r];
  }
}

extern "C" void kernel_launch(void* const* d_in, const int* in_sizes, int n_in,
                              void* d_out, int out_size, void* d_ws, size_t ws_size,
                              hipStream_t stream) {
  const float* Q = (const float*)d_in[0];
  const float* K = (const float*)d_in[1];
  const float* V = (const float*)d_in[2];
  const int*   M = (const int*)d_in[3];
  float* outv = (float*)d_out;
  float* outa = outv + (size_t)NB * NL * NH * NE;

  const size_t NQK = (size_t)NB * NH * NL * NE;
  short* Kbw = (short*)d_ws;
  short* Vtw = Kbw + NQK;
  unsigned long long* Mbp = (unsigned long long*)(Vtw + NQK);

  prep_all<<<dim3(7168), 256, 0, stream>>>(K, V, M, Kbw, Vtw, Mbp);
  attn_main<<<dim3(NB * (NL / 64) * NH), 256, 0, stream>>>(Q, Kbw, Vtw, Mbp, outv, outa);
}